// Round 11
// baseline (467.920 us; speedup 1.0000x reference)
//
#include <hip/hip_runtime.h>
#include <cstdint>
#include <cstddef>

#define N_NODES 1024
#define K_NEIGH 5
#define L_TIME  2016
#define PATCHSZ 12
#define EMBED   96
#define CINX    6
#define P_CNT   168
#define KDOT    72
#define OUT_PER_BN (EMBED * P_CNT)   // 16128

// d_ws layout (bytes): [0,20480) sampled ints; [24576,+18432) WH frags; then WL
#define WS_WH 24576
#define WS_WL (24576 + 18432)

typedef __attribute__((ext_vector_type(8))) short   bf16x8;
typedef __attribute__((ext_vector_type(4))) float   f32x4;
typedef __attribute__((ext_vector_type(4))) unsigned int u32x4;

// ---- bf16 split helpers (RNE) ----
__device__ __forceinline__ uint32_t f2bf_bits(float f) {
  uint32_t u = __float_as_uint(f);
  return (u + 0x7fffu + ((u >> 16) & 1u)) >> 16;
}
__device__ __forceinline__ float bf_hi_f(uint32_t hb) { return __uint_as_float(hb << 16); }

// ---------------- Threefry-2x32, JAX partitionable (validated) -------------
__device__ __forceinline__ uint32_t rotl32(uint32_t x, int r) {
  return (x << r) | (x >> (32 - r));
}
__device__ __forceinline__ uint32_t threefry_bits(uint32_t hi, uint32_t lo) {
  const uint32_t ks0 = 0u, ks1 = 42u;
  const uint32_t ks2 = ks0 ^ ks1 ^ 0x1BD11BDAu;
  uint32_t x0 = hi + ks0, x1 = lo + ks1;
#define TF_ROUND(r) { x0 += x1; x1 = rotl32(x1, (r)); x1 ^= x0; }
  TF_ROUND(13) TF_ROUND(15) TF_ROUND(26) TF_ROUND(6)
  x0 += ks1; x1 += ks2 + 1u;
  TF_ROUND(17) TF_ROUND(29) TF_ROUND(16) TF_ROUND(24)
  x0 += ks2; x1 += ks0 + 2u;
  TF_ROUND(13) TF_ROUND(15) TF_ROUND(26) TF_ROUND(6)
  x0 += ks0; x1 += ks1 + 3u;
  TF_ROUND(17) TF_ROUND(29) TF_ROUND(16) TF_ROUND(24)
  x0 += ks1; x1 += ks2 + 4u;
  TF_ROUND(13) TF_ROUND(15) TF_ROUND(26) TF_ROUND(6)
  x0 += ks2; x1 += ks0 + 5u;
#undef TF_ROUND
  return x0 ^ x1;
}
__device__ __forceinline__ float gumbel_from_bits(uint32_t bits) {
  float f = __uint_as_float((bits >> 9) | 0x3f800000u) - 1.0f;
  f = fmaxf(f, 1.17549435e-38f);
  return -logf(-logf(f));
}

// ---------------- Kernel 0: pre-pack W into A-frag hi/lo layout ------------
// Frag element (m,kc,L,j): w[o = m*16 + (L&15)][k = kc*32 + (L>>4)*8 + j],
// zero-padded for k>=72. Lane frag = 8 bf16 = 16 B contiguous.
__global__ __launch_bounds__(256)
void wpack_kernel(const float* __restrict__ wgt, char* __restrict__ ws) {
  const int tid = threadIdx.x;
  for (int t = tid; t < 1152; t += 256) {     // 18 (m*3+kc) x 64 lanes
    const int L  = t & 63;
    const int mk = t >> 6;
    const int kc = mk % 3;
    const int m  = mk / 3;
    const int o  = m * 16 + (L & 15);
    const int kbase = kc * 32 + (L >> 4) * 8;
    uint32_t hb[8], lb[8];
    #pragma unroll
    for (int j = 0; j < 8; ++j) {
      const int k = kbase + j;
      float v = (k < KDOT) ? wgt[o * KDOT + k] : 0.0f;
      hb[j] = f2bf_bits(v);
      lb[j] = f2bf_bits(v - bf_hi_f(hb[j]));
    }
    u32x4 ph, pl;
    #pragma unroll
    for (int i = 0; i < 4; ++i) {
      ph[i] = hb[2*i] | (hb[2*i+1] << 16);
      pl[i] = lb[2*i] | (lb[2*i+1] << 16);
    }
    *reinterpret_cast<u32x4*>(ws + WS_WH + mk * 1024 + L * 16) = ph;
    *reinterpret_cast<u32x4*>(ws + WS_WL + mk * 1024 + L * 16) = pl;
  }
}

// ---------------- Kernel 1: Gumbel-max sampling (unchanged R6) -------------
__global__ __launch_bounds__(1024)
void sample_kernel(const float* __restrict__ adj, int* __restrict__ sampled) {
  const int n = blockIdx.x;
  const int tid = threadIdx.x;
  const float la = logf(adj[(size_t)n * N_NODES + tid]);

  float best[K_NEIGH];
  int   bestj[K_NEIGH];
  #pragma unroll
  for (int k = 0; k < K_NEIGH; ++k) {
    uint32_t bits = threefry_bits(0u, (uint32_t)((n * K_NEIGH + k) * N_NODES + tid));
    best[k] = la + gumbel_from_bits(bits);
    bestj[k] = tid;
  }
  #pragma unroll
  for (int k = 0; k < K_NEIGH; ++k) {
    #pragma unroll
    for (int off = 32; off > 0; off >>= 1) {
      float ov = __shfl_down(best[k], off);
      int   oj = __shfl_down(bestj[k], off);
      if (ov > best[k] || (ov == best[k] && oj < bestj[k])) { best[k] = ov; bestj[k] = oj; }
    }
  }
  __shared__ float sv[16][K_NEIGH];
  __shared__ int   sj[16][K_NEIGH];
  if ((tid & 63) == 0) {
    #pragma unroll
    for (int k = 0; k < K_NEIGH; ++k) { sv[tid >> 6][k] = best[k]; sj[tid >> 6][k] = bestj[k]; }
  }
  __syncthreads();
  if (tid < K_NEIGH) {
    float b = sv[0][tid];
    int  bj = sj[0][tid];
    #pragma unroll
    for (int w = 1; w < 16; ++w) {
      if (sv[w][tid] > b || (sv[w][tid] == b && sj[w][tid] < bj)) { b = sv[w][tid]; bj = sj[w][tid]; }
    }
    sampled[n * K_NEIGH + tid] = bj;
  }
}

// 6-way select of a 32-bit offset by per-lane index (cndmask chain; avoids
// runtime-indexed array -> scratch, rule #20). c may be >=6 for padded
// k-octets; result is then unused (load is guarded).
__device__ __forceinline__ uint32_t sel6(uint32_t r0, uint32_t r1, uint32_t r2,
                                         uint32_t r3, uint32_t r4, uint32_t r5,
                                         int c) {
  uint32_t p = r0;
  p = (c == 1) ? r1 : p;
  p = (c == 2) ? r2 : p;
  p = (c == 3) ? r3 : p;
  p = (c == 4) ? r4 : p;
  p = (c == 5) ? r5 : p;
  return p;
}

// ---------------- Kernel 2: MFMA embed, W in LDS, 16 waves/CU --------------
// R10 post-mortem: W-in-VGPR (144 regs) pinned the kernel in the 8-waves/CU
// occupancy class; both pipes <15% busy -> latency-bound. W-frags are
// identical for all waves -> stage them ONCE per wg in LDS (36.9 KB, shared
// per CU) and read per tile via consecutive-16B ds_read_b128 (conflict-free).
// 32-bit row offsets (saddr+voffset) + bias in LDS shed the rest:
// ~110 VGPR, __launch_bounds__(256,4) -> 16 waves/CU, grid 4096 (1 bn/wg).
__global__ __launch_bounds__(256, 4)
void embed_kernel(const float* __restrict__ hist, const char* __restrict__ ws,
                  const float* __restrict__ bias, const int* __restrict__ sampled,
                  float* __restrict__ out) {
  __shared__ __align__(16) char smem[36864 + 384];
  u32x4* Wl = reinterpret_cast<u32x4*>(smem);          // [0,1152)=WH, [1152,2304)=WL
  float* Bl = reinterpret_cast<float*>(smem + 36864);  // 96 bias floats

  const int tid  = threadIdx.x;
  const int L    = tid & 63;
  const int wave = tid >> 6;
  const int g    = L >> 4;          // k-octet group within kc
  const int col  = L & 15;          // patch within tile

  // stage W-frags + bias into LDS (one copy serves all 4 waves)
  for (int i = tid; i < 2304; i += 256)
    Wl[i] = *reinterpret_cast<const u32x4*>(ws + WS_WH + (size_t)i * 16);
  if (tid < EMBED) Bl[tid] = bias[tid];

  const int bn = blockIdx.x;        // 0..4095
  const int n  = bn & (N_NODES - 1);
  const int b  = bn >> 10;

  // 6 source-row ELEMENT offsets (32-bit; hist < 2^25 elems)
  const uint32_t r0 = (uint32_t)bn * L_TIME;
  const uint32_t r1 = ((uint32_t)b * N_NODES + (uint32_t)sampled[n * K_NEIGH + 0]) * L_TIME;
  const uint32_t r2 = ((uint32_t)b * N_NODES + (uint32_t)sampled[n * K_NEIGH + 1]) * L_TIME;
  const uint32_t r3 = ((uint32_t)b * N_NODES + (uint32_t)sampled[n * K_NEIGH + 2]) * L_TIME;
  const uint32_t r4 = ((uint32_t)b * N_NODES + (uint32_t)sampled[n * K_NEIGH + 3]) * L_TIME;
  const uint32_t r5 = ((uint32_t)b * N_NODES + (uint32_t)sampled[n * K_NEIGH + 4]) * L_TIME;

  // per-lane k-octet source offsets: gk = kc*32 + g*8 spans rows c0(t0), c1(t1)
  uint32_t o0[3], o1[3];
  #pragma unroll
  for (int kc = 0; kc < 3; ++kc) {
    const int gk = kc * 32 + g * 8;
    const int c0 = gk / 12,       t0 = gk - c0 * 12;
    const int c1 = (gk + 4) / 12, t1 = (gk + 4) - c1 * 12;
    o0[kc] = sel6(r0, r1, r2, r3, r4, r5, c0) + (uint32_t)t0;
    o1[kc] = sel6(r0, r1, r2, r3, r4, r5, c1) + (uint32_t)t1;
  }

  __syncthreads();                  // W/bias visible

  float* outbn = out + (size_t)bn * OUT_PER_BN;

  #pragma unroll
  for (int t = 0; t < 3; ++t) {
    const int ntl = wave * 3 + t;   // wave-uniform tile id; wave3: 9,10 only
    if (ntl < 11) {
      const int p = ntl * 16 + col; // 0..175
      const bool pok = (p < P_CNT);
      f32x4 acc[6];
      #pragma unroll
      for (int m = 0; m < 6; ++m) acc[m] = {0.f, 0.f, 0.f, 0.f};

      #pragma unroll
      for (int kc = 0; kc < 3; ++kc) {
        u32x4 ph = {0,0,0,0}, pl = {0,0,0,0};
        if (pok && (kc < 2 || g == 0)) {        // gk<72
          const float4 f0 = *reinterpret_cast<const float4*>(hist + o0[kc] + (uint32_t)p * PATCHSZ);
          const float4 f1 = *reinterpret_cast<const float4*>(hist + o1[kc] + (uint32_t)p * PATCHSZ);
          const float v[8] = {f0.x, f0.y, f0.z, f0.w, f1.x, f1.y, f1.z, f1.w};
          uint32_t hb[8], lb[8];
          #pragma unroll
          for (int j = 0; j < 8; ++j) {
            hb[j] = f2bf_bits(v[j]);
            lb[j] = f2bf_bits(v[j] - bf_hi_f(hb[j]));
          }
          #pragma unroll
          for (int i = 0; i < 4; ++i) {
            ph[i] = hb[2*i] | (hb[2*i+1] << 16);
            pl[i] = lb[2*i] | (lb[2*i+1] << 16);
          }
        }
        const bf16x8 xh = __builtin_bit_cast(bf16x8, ph);
        const bf16x8 xl = __builtin_bit_cast(bf16x8, pl);
        #pragma unroll
        for (int m = 0; m < 6; ++m) {
          const int mk = m * 3 + kc;
          const bf16x8 whf = __builtin_bit_cast(bf16x8, Wl[mk * 64 + L]);
          const bf16x8 wlf = __builtin_bit_cast(bf16x8, Wl[1152 + mk * 64 + L]);
          acc[m] = __builtin_amdgcn_mfma_f32_16x16x32_bf16(whf, xh, acc[m], 0, 0, 0);
          acc[m] = __builtin_amdgcn_mfma_f32_16x16x32_bf16(whf, xl, acc[m], 0, 0, 0);
          acc[m] = __builtin_amdgcn_mfma_f32_16x16x32_bf16(wlf, xh, acc[m], 0, 0, 0);
        }
      }
      if (pok) {
        #pragma unroll
        for (int m = 0; m < 6; ++m) {
          const f32x4 bb = *reinterpret_cast<const f32x4*>(&Bl[m * 16 + g * 4]);
          #pragma unroll
          for (int i = 0; i < 4; ++i)
            __builtin_nontemporal_store(acc[m][i] + bb[i],
                                        &outbn[(size_t)(m * 16 + g * 4 + i) * P_CNT + p]);
        }
      }
    }
  }
}

// ---------------- launch ----------------
extern "C" void kernel_launch(void* const* d_in, const int* in_sizes, int n_in,
                              void* d_out, int out_size, void* d_ws, size_t ws_size,
                              hipStream_t stream) {
  const float* hist = (const float*)d_in[0];  // [4,1024,1,2016]
  const float* adj  = (const float*)d_in[1];  // [1024,1024]
  const float* wgt  = (const float*)d_in[2];  // [96,6,12]
  const float* bias = (const float*)d_in[3];  // [96]
  float* out = (float*)d_out;                 // [4,1024,96,168]
  char* ws   = (char*)d_ws;                   // sampled @0, W-frags @24576
  int* sampled = (int*)d_ws;

  wpack_kernel<<<dim3(1), dim3(256), 0, stream>>>(wgt, ws);
  sample_kernel<<<dim3(N_NODES), dim3(1024), 0, stream>>>(adj, sampled);
  embed_kernel<<<dim3(4 * N_NODES), dim3(256), 0, stream>>>(hist, ws, bias, sampled, out);
}